// Round 4
// baseline (1416.203 us; speedup 1.0000x reference)
//
#include <hip/hip_runtime.h>

// N = 100000 nodes, E = 1600000 edges, IN=128, HID=128, LAT=64
// edge_index arrives on device as int32 (harness converts integer inputs).
//
// CSR build (counting sort) + fused gather-mean + dense SAGE layers.
// Gather is latency-bound: unroll x4 with contiguous per-half adj chunks
// for 4 in-flight row fetches; 512-thread blocks for 32 waves/CU.

// ---------------- degree (int): deg[dst]++ ----------------
__global__ void k_deg(const int* __restrict__ dst, int* __restrict__ deg, int E, int nNodes) {
    int i = blockIdx.x * blockDim.x + threadIdx.x;
    if (i < E) {
        unsigned d = (unsigned)dst[i];
        if (d < (unsigned)nNodes) atomicAdd(&deg[d], 1);
    }
}

// ---------------- scan stage 1 ----------------
__global__ void k_scan1(const int* __restrict__ deg, int* __restrict__ off,
                        int* __restrict__ bs, int nNodes) {
    __shared__ int tmp[256];
    int t = threadIdx.x;
    int i = blockIdx.x * 256 + t;
    int v = (i < nNodes) ? deg[i] : 0;
    tmp[t] = v;
    __syncthreads();
    for (int d = 1; d < 256; d <<= 1) {
        int add = (t >= d) ? tmp[t - d] : 0;
        __syncthreads();
        tmp[t] += add;
        __syncthreads();
    }
    if (i < nNodes) off[i] = tmp[t] - v;
    if (t == 255) bs[blockIdx.x] = tmp[255];
}

// ---------------- scan stage 2 (1 block) ----------------
__global__ void k_scan2(int* __restrict__ bs, int nb) {
    __shared__ int tmp[512];
    int t = threadIdx.x;
    int carry = 0;
    for (int start = 0; start < nb; start += 512) {
        int i = start + t;
        int v = (i < nb) ? bs[i] : 0;
        tmp[t] = v;
        __syncthreads();
        for (int d = 1; d < 512; d <<= 1) {
            int add = (t >= d) ? tmp[t - d] : 0;
            __syncthreads();
            tmp[t] += add;
            __syncthreads();
        }
        int incl = tmp[t];
        if (i < nb) bs[i] = incl - v + carry;
        int total = tmp[511];
        __syncthreads();
        carry += total;
    }
}

// ---------------- scan stage 3 ----------------
__global__ void k_scan3(int* __restrict__ off, const int* __restrict__ bs, int nNodes) {
    int i = blockIdx.x * 256 + threadIdx.x;
    if (i < nNodes) off[i] += bs[blockIdx.x];
}

// ---------------- CSR fill ----------------
__global__ void k_fill(const int* __restrict__ src, const int* __restrict__ dst,
                       const int* __restrict__ off, int* __restrict__ cur,
                       int* __restrict__ adj, int E, int nNodes) {
    int i = blockIdx.x * blockDim.x + threadIdx.x;
    if (i < E) {
        unsigned d = (unsigned)dst[i];
        unsigned s = (unsigned)src[i];
        if (d < (unsigned)nNodes && s < (unsigned)nNodes) {
            int pos = atomicAdd(&cur[d], 1);
            adj[off[d] + pos] = (int)s;
        }
    }
}

// ---------------- gather-mean helper (device) ----------------
// Each wave handles 4 rows; halves (32 lanes) take contiguous adj chunks,
// unrolled x4 for memory-level parallelism. Result written to ms[row][].
__device__ __forceinline__ void gather_rows(const float* __restrict__ feat,
                                            const int* __restrict__ adj,
                                            const int* __restrict__ off,
                                            const int* __restrict__ deg,
                                            float (*ms)[128],
                                            int base, int nNodes, int tid) {
    int w = tid >> 6, lane = tid & 63;
    int half = lane >> 5, l32 = lane & 31;
    const float4* feat4 = (const float4*)feat;
    for (int r = w * 4; r < w * 4 + 4; ++r) {
        int n = base + r;
        float4 a = make_float4(0.f, 0.f, 0.f, 0.f);
        float inv = 1.f;
        if (n < nNodes) {
            int o0 = off[n];
            int dg = deg[n];
            int n0 = (dg + 1) >> 1;               // half 0 gets first n0
            int kb = half ? (o0 + n0) : o0;
            int ke = half ? (o0 + dg) : (o0 + n0);
            int k = kb;
            for (; k + 4 <= ke; k += 4) {
                int s0 = adj[k + 0];
                int s1 = adj[k + 1];
                int s2 = adj[k + 2];
                int s3 = adj[k + 3];
                float4 v0 = feat4[(long long)s0 * 32 + l32];
                float4 v1 = feat4[(long long)s1 * 32 + l32];
                float4 v2 = feat4[(long long)s2 * 32 + l32];
                float4 v3 = feat4[(long long)s3 * 32 + l32];
                a.x += v0.x + v1.x + v2.x + v3.x;
                a.y += v0.y + v1.y + v2.y + v3.y;
                a.z += v0.z + v1.z + v2.z + v3.z;
                a.w += v0.w + v1.w + v2.w + v3.w;
            }
            for (; k < ke; ++k) {
                int s = adj[k];
                float4 v = feat4[(long long)s * 32 + l32];
                a.x += v.x; a.y += v.y; a.z += v.z; a.w += v.w;
            }
            inv = 1.f / fmaxf((float)dg, 1.f);
        }
        a.x += __shfl_xor(a.x, 32);
        a.y += __shfl_xor(a.y, 32);
        a.z += __shfl_xor(a.z, 32);
        a.w += __shfl_xor(a.w, 32);
        if (half == 0) {
            a.x *= inv; a.y *= inv; a.z *= inv; a.w *= inv;
            ((float4*)&ms[r][0])[l32] = a;
        }
    }
}

// ---------------- fused gather + SAGE layer 1 ----------------
// 32 nodes/block, 512 threads (8 waves).
__launch_bounds__(512)
__global__ void k_sage1(const float* __restrict__ x,
                        const int* __restrict__ adj, const int* __restrict__ off,
                        const int* __restrict__ deg,
                        const float* __restrict__ Wl, const float* __restrict__ bl,
                        const float* __restrict__ Wr,
                        float* __restrict__ h, int nNodes) {
    __shared__ float xs[32][128];
    __shared__ float ms[32][128];
    int tid = threadIdx.x;
    int base = blockIdx.x * 32;

    for (int i = tid; i < 32 * 32; i += 512) {
        int row = i >> 5, col4 = i & 31;
        int n = base + row;
        float4 xv = make_float4(0.f, 0.f, 0.f, 0.f);
        if (n < nNodes) xv = ((const float4*)x)[(long long)n * 32 + col4];
        ((float4*)&xs[row][0])[col4] = xv;
    }

    gather_rows(x, adj, off, deg, ms, base, nNodes, tid);
    __syncthreads();

    // dense: 128 ch x 4 row-groups, 8 rows/thread
    int ch = tid & 127;
    int g  = tid >> 7;
    float acc[8];
#pragma unroll
    for (int i = 0; i < 8; ++i) acc[i] = 0.f;

    const float4* wr = (const float4*)&Wr[ch * 128];
    const float4* wl = (const float4*)&Wl[ch * 128];
    for (int kc = 0; kc < 32; ++kc) {
        float4 wr4 = wr[kc];
        float4 wl4 = wl[kc];
#pragma unroll
        for (int i = 0; i < 8; ++i) {
            int row = g * 8 + i;
            float4 xv = ((const float4*)&xs[row][0])[kc];
            float4 mv = ((const float4*)&ms[row][0])[kc];
            acc[i] += xv.x * wr4.x + xv.y * wr4.y + xv.z * wr4.z + xv.w * wr4.w
                    + mv.x * wl4.x + mv.y * wl4.y + mv.z * wl4.z + mv.w * wl4.w;
        }
    }
    float bias = bl[ch];
#pragma unroll
    for (int i = 0; i < 8; ++i) {
        int n = base + g * 8 + i;
        if (n < nNodes) h[(long long)n * 128 + ch] = fmaxf(acc[i] + bias, 0.f);
    }
}

// ---------------- fused gather + SAGE layer 2 (64 out ch, no relu) ----------------
__launch_bounds__(512)
__global__ void k_sage2(const float* __restrict__ hin,
                        const int* __restrict__ adj, const int* __restrict__ off,
                        const int* __restrict__ deg,
                        const float* __restrict__ Wl, const float* __restrict__ bl,
                        const float* __restrict__ Wr,
                        float* __restrict__ z, int nNodes) {
    __shared__ float xs[32][128];
    __shared__ float ms[32][128];
    int tid = threadIdx.x;
    int base = blockIdx.x * 32;

    for (int i = tid; i < 32 * 32; i += 512) {
        int row = i >> 5, col4 = i & 31;
        int n = base + row;
        float4 xv = make_float4(0.f, 0.f, 0.f, 0.f);
        if (n < nNodes) xv = ((const float4*)hin)[(long long)n * 32 + col4];
        ((float4*)&xs[row][0])[col4] = xv;
    }

    gather_rows(hin, adj, off, deg, ms, base, nNodes, tid);
    __syncthreads();

    // dense: 64 ch x 8 row-groups, 4 rows/thread
    int ch = tid & 63;
    int g  = tid >> 6;
    float acc[4];
#pragma unroll
    for (int i = 0; i < 4; ++i) acc[i] = 0.f;

    const float4* wr = (const float4*)&Wr[ch * 128];
    const float4* wl = (const float4*)&Wl[ch * 128];
    for (int kc = 0; kc < 32; ++kc) {
        float4 wr4 = wr[kc];
        float4 wl4 = wl[kc];
#pragma unroll
        for (int i = 0; i < 4; ++i) {
            int row = g * 4 + i;
            float4 xv = ((const float4*)&xs[row][0])[kc];
            float4 mv = ((const float4*)&ms[row][0])[kc];
            acc[i] += xv.x * wr4.x + xv.y * wr4.y + xv.z * wr4.z + xv.w * wr4.w
                    + mv.x * wl4.x + mv.y * wl4.y + mv.z * wl4.z + mv.w * wl4.w;
        }
    }
    float bias = bl[ch];
#pragma unroll
    for (int i = 0; i < 4; ++i) {
        int n = base + g * 4 + i;
        if (n < nNodes) z[(long long)n * 64 + ch] = acc[i] + bias;
    }
}

// ---------------- decoder: out = z @ W_dec^T + b_dec ----------------
__launch_bounds__(512)
__global__ void k_dec(const float* __restrict__ z, const float* __restrict__ W,
                      const float* __restrict__ b,
                      float* __restrict__ out, int nNodes) {
    __shared__ float zs[32][64];
    int tid = threadIdx.x;
    int base = blockIdx.x * 32;

    for (int i = tid; i < 32 * 16; i += 512) {
        int row = i >> 4, col4 = i & 15;
        int n = base + row;
        float4 zv = make_float4(0.f, 0.f, 0.f, 0.f);
        if (n < nNodes) zv = ((const float4*)z)[(long long)n * 16 + col4];
        ((float4*)&zs[row][0])[col4] = zv;
    }
    __syncthreads();

    // 128 ch x 4 row-groups, 8 rows/thread, K=64
    int ch = tid & 127;
    int g  = tid >> 7;
    float acc[8];
#pragma unroll
    for (int i = 0; i < 8; ++i) acc[i] = 0.f;

    const float4* w = (const float4*)&W[ch * 64];
    for (int kc = 0; kc < 16; ++kc) {
        float4 w4 = w[kc];
#pragma unroll
        for (int i = 0; i < 8; ++i) {
            int row = g * 8 + i;
            float4 zv = ((const float4*)&zs[row][0])[kc];
            acc[i] += zv.x * w4.x + zv.y * w4.y + zv.z * w4.z + zv.w * w4.w;
        }
    }
    float bias = b[ch];
#pragma unroll
    for (int i = 0; i < 8; ++i) {
        int n = base + g * 8 + i;
        if (n < nNodes) out[(long long)n * 128 + ch] = acc[i] + bias;
    }
}

extern "C" void kernel_launch(void* const* d_in, const int* in_sizes, int n_in,
                              void* d_out, int out_size, void* d_ws, size_t ws_size,
                              hipStream_t stream) {
    const float* x    = (const float*)d_in[0];
    const int*   ei   = (const int*)d_in[1];   // int32 on device
    const float* W1l  = (const float*)d_in[2];
    const float* b1l  = (const float*)d_in[3];
    const float* W1r  = (const float*)d_in[4];
    const float* W2l  = (const float*)d_in[5];
    const float* b2l  = (const float*)d_in[6];
    const float* W2r  = (const float*)d_in[7];
    const float* Wdec = (const float*)d_in[8];
    const float* bdec = (const float*)d_in[9];

    const int N = in_sizes[0] / 128;
    const int E = in_sizes[1] / 2;
    const int nb = (N + 255) / 256;

    const int* src = ei;
    const int* dst = ei + E;

    // ws layout (ints): adj[E] | deg[N] | cur[N] | off[N] | bs[nb]
    int* adj = (int*)d_ws;
    int* deg = adj + E;
    int* cur = deg + N;
    int* off = cur + N;
    int* bs  = off + N;

    hipMemsetAsync(deg, 0, (size_t)2 * N * sizeof(int), stream);

    k_deg  <<<(E + 255) / 256, 256, 0, stream>>>(dst, deg, E, N);
    k_scan1<<<nb, 256, 0, stream>>>(deg, off, bs, N);
    k_scan2<<<1, 512, 0, stream>>>(bs, nb);
    k_scan3<<<nb, 256, 0, stream>>>(off, bs, N);
    k_fill <<<(E + 255) / 256, 256, 0, stream>>>(src, dst, off, cur, adj, E, N);

    // d_out layout: x_recon [N*128] then z [N*64]; park h in x_recon region
    float* outp = (float*)d_out;
    float* h    = outp;
    float* z    = outp + (long long)N * 128;
    float* xrec = outp;

    const int nblk = (N + 31) / 32;
    k_sage1<<<nblk, 512, 0, stream>>>(x, adj, off, deg, W1l, b1l, W1r, h, N);
    k_sage2<<<nblk, 512, 0, stream>>>(h, adj, off, deg, W2l, b2l, W2r, z, N);
    k_dec  <<<nblk, 512, 0, stream>>>(z, Wdec, bdec, xrec, N);
}

// Round 5
// 728.958 us; speedup vs baseline: 1.9428x; 1.9428x over previous
//
#include <hip/hip_runtime.h>

// N = 100000 nodes, E = 1600000 edges, IN=128, HID=128, LAT=64
// edge_index arrives on device as int32 (harness converts integer inputs).
//
// Round-3 structure (256-thread blocks) + ONE change: gather loop unrolled
// x4 (stride-2 interleaved halves) for 4 in-flight neighbor-row fetches.

// ---------------- degree (int): deg[dst]++ ----------------
__global__ void k_deg(const int* __restrict__ dst, int* __restrict__ deg, int E, int nNodes) {
    int i = blockIdx.x * blockDim.x + threadIdx.x;
    if (i < E) {
        unsigned d = (unsigned)dst[i];
        if (d < (unsigned)nNodes) atomicAdd(&deg[d], 1);
    }
}

// ---------------- scan stage 1 ----------------
__global__ void k_scan1(const int* __restrict__ deg, int* __restrict__ off,
                        int* __restrict__ bs, int nNodes) {
    __shared__ int tmp[256];
    int t = threadIdx.x;
    int i = blockIdx.x * 256 + t;
    int v = (i < nNodes) ? deg[i] : 0;
    tmp[t] = v;
    __syncthreads();
    for (int d = 1; d < 256; d <<= 1) {
        int add = (t >= d) ? tmp[t - d] : 0;
        __syncthreads();
        tmp[t] += add;
        __syncthreads();
    }
    if (i < nNodes) off[i] = tmp[t] - v;
    if (t == 255) bs[blockIdx.x] = tmp[255];
}

// ---------------- scan stage 2 (1 block) ----------------
__global__ void k_scan2(int* __restrict__ bs, int nb) {
    __shared__ int tmp[512];
    int t = threadIdx.x;
    int carry = 0;
    for (int start = 0; start < nb; start += 512) {
        int i = start + t;
        int v = (i < nb) ? bs[i] : 0;
        tmp[t] = v;
        __syncthreads();
        for (int d = 1; d < 512; d <<= 1) {
            int add = (t >= d) ? tmp[t - d] : 0;
            __syncthreads();
            tmp[t] += add;
            __syncthreads();
        }
        int incl = tmp[t];
        if (i < nb) bs[i] = incl - v + carry;
        int total = tmp[511];
        __syncthreads();
        carry += total;
    }
}

// ---------------- scan stage 3 ----------------
__global__ void k_scan3(int* __restrict__ off, const int* __restrict__ bs, int nNodes) {
    int i = blockIdx.x * 256 + threadIdx.x;
    if (i < nNodes) off[i] += bs[blockIdx.x];
}

// ---------------- CSR fill ----------------
__global__ void k_fill(const int* __restrict__ src, const int* __restrict__ dst,
                       const int* __restrict__ off, int* __restrict__ cur,
                       int* __restrict__ adj, int E, int nNodes) {
    int i = blockIdx.x * blockDim.x + threadIdx.x;
    if (i < E) {
        unsigned d = (unsigned)dst[i];
        unsigned s = (unsigned)src[i];
        if (d < (unsigned)nNodes && s < (unsigned)nNodes) {
            int pos = atomicAdd(&cur[d], 1);
            adj[off[d] + pos] = (int)s;
        }
    }
}

// ---------------- gather-mean helper: wave w handles rows w*8..w*8+7 ----------------
// halves (32 lanes) take even/odd neighbors (k = o0+half, step 2), UNROLLED x4:
// 4 independent row fetches in flight per half (8 per wave).
__device__ __forceinline__ void gather_rows(const float* __restrict__ feat,
                                            const int* __restrict__ adj,
                                            const int* __restrict__ off,
                                            const int* __restrict__ deg,
                                            float (*ms)[128],
                                            int base, int nNodes, int tid) {
    int w = tid >> 6, lane = tid & 63;
    int half = lane >> 5, l32 = lane & 31;
    const float4* feat4 = (const float4*)feat;
    for (int r = w * 8; r < w * 8 + 8; ++r) {
        int n = base + r;
        float4 a = make_float4(0.f, 0.f, 0.f, 0.f);
        float inv = 1.f;
        if (n < nNodes) {
            int o0 = off[n];
            int dg = deg[n];
            int o1 = o0 + dg;
            int k = o0 + half;
            for (; k + 6 < o1; k += 8) {         // 4 neighbors per half per iter
                int s0 = adj[k + 0];
                int s1 = adj[k + 2];
                int s2 = adj[k + 4];
                int s3 = adj[k + 6];
                float4 v0 = feat4[(long long)s0 * 32 + l32];
                float4 v1 = feat4[(long long)s1 * 32 + l32];
                float4 v2 = feat4[(long long)s2 * 32 + l32];
                float4 v3 = feat4[(long long)s3 * 32 + l32];
                a.x += v0.x + v1.x + v2.x + v3.x;
                a.y += v0.y + v1.y + v2.y + v3.y;
                a.z += v0.z + v1.z + v2.z + v3.z;
                a.w += v0.w + v1.w + v2.w + v3.w;
            }
            for (; k < o1; k += 2) {
                int s = adj[k];
                float4 v = feat4[(long long)s * 32 + l32];
                a.x += v.x; a.y += v.y; a.z += v.z; a.w += v.w;
            }
            inv = 1.f / fmaxf((float)dg, 1.f);
        }
        a.x += __shfl_xor(a.x, 32);
        a.y += __shfl_xor(a.y, 32);
        a.z += __shfl_xor(a.z, 32);
        a.w += __shfl_xor(a.w, 32);
        if (half == 0) {
            a.x *= inv; a.y *= inv; a.z *= inv; a.w *= inv;
            ((float4*)&ms[r][0])[l32] = a;
        }
    }
}

// ---------------- fused gather + SAGE layer 1 ----------------
// 32 nodes/block, 256 threads (4 waves).
__launch_bounds__(256)
__global__ void k_sage1(const float* __restrict__ x,
                        const int* __restrict__ adj, const int* __restrict__ off,
                        const int* __restrict__ deg,
                        const float* __restrict__ Wl, const float* __restrict__ bl,
                        const float* __restrict__ Wr,
                        float* __restrict__ h, int nNodes) {
    __shared__ float xs[32][128];
    __shared__ float ms[32][128];
    int tid = threadIdx.x;
    int base = blockIdx.x * 32;

    for (int i = tid; i < 32 * 32; i += 256) {
        int row = i >> 5, col4 = i & 31;
        int n = base + row;
        float4 xv = make_float4(0.f, 0.f, 0.f, 0.f);
        if (n < nNodes) xv = ((const float4*)x)[(long long)n * 32 + col4];
        ((float4*)&xs[row][0])[col4] = xv;
    }

    gather_rows(x, adj, off, deg, ms, base, nNodes, tid);
    __syncthreads();

    // dense: 128 ch x 2 node-groups, 16 rows/thread
    int ch = tid & 127;
    int g  = tid >> 7;
    float acc[16];
#pragma unroll
    for (int i = 0; i < 16; ++i) acc[i] = 0.f;

    const float4* wr = (const float4*)&Wr[ch * 128];
    const float4* wl = (const float4*)&Wl[ch * 128];
    for (int kc = 0; kc < 32; ++kc) {
        float4 wr4 = wr[kc];
        float4 wl4 = wl[kc];
#pragma unroll
        for (int i = 0; i < 16; ++i) {
            int row = g * 16 + i;
            float4 xv = ((const float4*)&xs[row][0])[kc];
            float4 mv = ((const float4*)&ms[row][0])[kc];
            acc[i] += xv.x * wr4.x + xv.y * wr4.y + xv.z * wr4.z + xv.w * wr4.w
                    + mv.x * wl4.x + mv.y * wl4.y + mv.z * wl4.z + mv.w * wl4.w;
        }
    }
    float bias = bl[ch];
#pragma unroll
    for (int i = 0; i < 16; ++i) {
        int n = base + g * 16 + i;
        if (n < nNodes) h[(long long)n * 128 + ch] = fmaxf(acc[i] + bias, 0.f);
    }
}

// ---------------- fused gather + SAGE layer 2 (64 out ch, no relu) ----------------
__launch_bounds__(256)
__global__ void k_sage2(const float* __restrict__ hin,
                        const int* __restrict__ adj, const int* __restrict__ off,
                        const int* __restrict__ deg,
                        const float* __restrict__ Wl, const float* __restrict__ bl,
                        const float* __restrict__ Wr,
                        float* __restrict__ z, int nNodes) {
    __shared__ float xs[32][128];
    __shared__ float ms[32][128];
    int tid = threadIdx.x;
    int base = blockIdx.x * 32;

    for (int i = tid; i < 32 * 32; i += 256) {
        int row = i >> 5, col4 = i & 31;
        int n = base + row;
        float4 xv = make_float4(0.f, 0.f, 0.f, 0.f);
        if (n < nNodes) xv = ((const float4*)hin)[(long long)n * 32 + col4];
        ((float4*)&xs[row][0])[col4] = xv;
    }

    gather_rows(hin, adj, off, deg, ms, base, nNodes, tid);
    __syncthreads();

    // dense: 64 ch x 4 node-groups, 8 rows/thread
    int ch = tid & 63;
    int g  = tid >> 6;
    float acc[8];
#pragma unroll
    for (int i = 0; i < 8; ++i) acc[i] = 0.f;

    const float4* wr = (const float4*)&Wr[ch * 128];
    const float4* wl = (const float4*)&Wl[ch * 128];
    for (int kc = 0; kc < 32; ++kc) {
        float4 wr4 = wr[kc];
        float4 wl4 = wl[kc];
#pragma unroll
        for (int i = 0; i < 8; ++i) {
            int row = g * 8 + i;
            float4 xv = ((const float4*)&xs[row][0])[kc];
            float4 mv = ((const float4*)&ms[row][0])[kc];
            acc[i] += xv.x * wr4.x + xv.y * wr4.y + xv.z * wr4.z + xv.w * wr4.w
                    + mv.x * wl4.x + mv.y * wl4.y + mv.z * wl4.z + mv.w * wl4.w;
        }
    }
    float bias = bl[ch];
#pragma unroll
    for (int i = 0; i < 8; ++i) {
        int n = base + g * 8 + i;
        if (n < nNodes) z[(long long)n * 64 + ch] = acc[i] + bias;
    }
}

// ---------------- decoder: out = z @ W_dec^T + b_dec (Round-3 version) ----------------
__launch_bounds__(256)
__global__ void k_dec(const float* __restrict__ z, const float* __restrict__ W,
                      const float* __restrict__ b,
                      float* __restrict__ out, int nNodes) {
    __shared__ float zs[32][64];
    int tid = threadIdx.x;
    int base = blockIdx.x * 32;

    for (int i = tid; i < 32 * 16; i += 256) {
        int row = i >> 4, col4 = i & 15;
        int n = base + row;
        float4 zv = make_float4(0.f, 0.f, 0.f, 0.f);
        if (n < nNodes) zv = ((const float4*)z)[(long long)n * 16 + col4];
        ((float4*)&zs[row][0])[col4] = zv;
    }
    __syncthreads();

    int ch = tid & 127;
    int g  = tid >> 7;
    float acc[16];
#pragma unroll
    for (int i = 0; i < 16; ++i) acc[i] = 0.f;

    const float4* w = (const float4*)&W[ch * 64];
    for (int kc = 0; kc < 16; ++kc) {
        float4 w4 = w[kc];
#pragma unroll
        for (int i = 0; i < 16; ++i) {
            int row = g * 16 + i;
            float4 zv = ((const float4*)&zs[row][0])[kc];
            acc[i] += zv.x * w4.x + zv.y * w4.y + zv.z * w4.z + zv.w * w4.w;
        }
    }
    float bias = b[ch];
#pragma unroll
    for (int i = 0; i < 16; ++i) {
        int n = base + g * 16 + i;
        if (n < nNodes) out[(long long)n * 128 + ch] = acc[i] + bias;
    }
}

extern "C" void kernel_launch(void* const* d_in, const int* in_sizes, int n_in,
                              void* d_out, int out_size, void* d_ws, size_t ws_size,
                              hipStream_t stream) {
    const float* x    = (const float*)d_in[0];
    const int*   ei   = (const int*)d_in[1];   // int32 on device
    const float* W1l  = (const float*)d_in[2];
    const float* b1l  = (const float*)d_in[3];
    const float* W1r  = (const float*)d_in[4];
    const float* W2l  = (const float*)d_in[5];
    const float* b2l  = (const float*)d_in[6];
    const float* W2r  = (const float*)d_in[7];
    const float* Wdec = (const float*)d_in[8];
    const float* bdec = (const float*)d_in[9];

    const int N = in_sizes[0] / 128;
    const int E = in_sizes[1] / 2;
    const int nb = (N + 255) / 256;

    const int* src = ei;
    const int* dst = ei + E;

    // ws layout (ints): adj[E] | deg[N] | cur[N] | off[N] | bs[nb]
    int* adj = (int*)d_ws;
    int* deg = adj + E;
    int* cur = deg + N;
    int* off = cur + N;
    int* bs  = off + N;

    hipMemsetAsync(deg, 0, (size_t)2 * N * sizeof(int), stream);

    k_deg  <<<(E + 255) / 256, 256, 0, stream>>>(dst, deg, E, N);
    k_scan1<<<nb, 256, 0, stream>>>(deg, off, bs, N);
    k_scan2<<<1, 512, 0, stream>>>(bs, nb);
    k_scan3<<<nb, 256, 0, stream>>>(off, bs, N);
    k_fill <<<(E + 255) / 256, 256, 0, stream>>>(src, dst, off, cur, adj, E, N);

    // d_out layout: x_recon [N*128] then z [N*64]; park h in x_recon region
    float* outp = (float*)d_out;
    float* h    = outp;
    float* z    = outp + (long long)N * 128;
    float* xrec = outp;

    const int nblk = (N + 31) / 32;
    k_sage1<<<nblk, 256, 0, stream>>>(x, adj, off, deg, W1l, b1l, W1r, h, N);
    k_sage2<<<nblk, 256, 0, stream>>>(h, adj, off, deg, W2l, b2l, W2r, z, N);
    k_dec  <<<nblk, 256, 0, stream>>>(z, Wdec, bdec, xrec, N);
}